// Round 3
// baseline (14827.994 us; speedup 1.0000x reference)
//
#include <hip/hip_runtime.h>
#include <stdint.h>

#define DEPTH 12
#define DD    768
#define HH    12
#define HDIM  64
#define FFN   3072
#define BB    64
#define LQn   577
#define SKn   64
#define MQ    (BB*LQn)      // 36928
#define MQP   36992         // 289*128
#define MKV   (BB*SKn)      // 4096
#define CHROWS 8192         // FFN M-chunk (64 blocks of 128)

typedef unsigned short u16;
typedef __bf16 bf16x8 __attribute__((ext_vector_type(8)));
typedef float  f32x4  __attribute__((ext_vector_type(4)));

__device__ __forceinline__ u16 f2bf(float f) {
    union { float f; unsigned int u; } v; v.f = f;
    unsigned int r = v.u + 0x7fffu + ((v.u >> 16) & 1u);
    return (u16)(r >> 16);
}

__device__ __forceinline__ void gload_lds16(const void* g, void* l) {
    __builtin_amdgcn_global_load_lds(
        (__attribute__((address_space(1))) void*)(uintptr_t)g,
        (__attribute__((address_space(3))) void*)l,
        16, 0, 0);
}

// ---------------- GEMM: C[M,N] = A[M,K] @ W[N,K]^T + bias ----------------
// EPI 0: store bf16   1: gelu->bf16   2: resid(f32) += v (row<Mvalid)
template<int EPI>
__global__ __launch_bounds__(256)
void gemm_bt(const u16* __restrict__ A, int lda,
             const u16* __restrict__ Bw, int ldb,
             const float* __restrict__ bias,
             u16* __restrict__ outb, float* __restrict__ resid,
             int ldo, int Mvalid, int K)
{
    __shared__ __align__(16) u16 sA[128*64];
    __shared__ __align__(16) u16 sB[128*64];

    const int tid  = threadIdx.x;
    const int wave = tid >> 6, lane = tid & 63;
    const int bm = blockIdx.x, bn = blockIdx.y;
    const int wm = (wave >> 1) * 64, wn = (wave & 1) * 64;
    const int lr = lane & 15;
    const int lk = (lane >> 4) * 8;
    const int c8 = (tid & 7) * 8;

    f32x4 acc[4][4] = {};

    const u16* Ab = A  + (size_t)bm * 128 * lda;
    const u16* Bb = Bw + (size_t)bn * 128 * ldb;

    for (int k0 = 0; k0 < K; k0 += 64) {
        #pragma unroll
        for (int i = 0; i < 4; ++i) {
            int r = (i * 256 + tid) >> 3;
            gload_lds16(Ab + (size_t)r * lda + k0 + c8, sA + (i*4 + wave) * 512);
            gload_lds16(Bb + (size_t)r * ldb + k0 + c8, sB + (i*4 + wave) * 512);
        }
        __syncthreads();
        #pragma unroll
        for (int kk = 0; kk < 2; ++kk) {
            bf16x8 af[4], bfr[4];
            #pragma unroll
            for (int m = 0; m < 4; ++m)
                af[m] = *(const bf16x8*)(sA + (wm + m*16 + lr)*64 + kk*32 + lk);
            #pragma unroll
            for (int n = 0; n < 4; ++n)
                bfr[n] = *(const bf16x8*)(sB + (wn + n*16 + lr)*64 + kk*32 + lk);
            #pragma unroll
            for (int m = 0; m < 4; ++m)
                #pragma unroll
                for (int n = 0; n < 4; ++n)
                    acc[m][n] = __builtin_amdgcn_mfma_f32_16x16x32_bf16(af[m], bfr[n], acc[m][n], 0, 0, 0);
        }
        __syncthreads();
    }

    const int rowbase = bm*128 + wm + (lane >> 4) * 4;
    const int colbase = bn*128 + wn + lr;
    float bias_n[4];
    #pragma unroll
    for (int n = 0; n < 4; ++n) bias_n[n] = bias[colbase + n*16];

    #pragma unroll
    for (int m = 0; m < 4; ++m) {
        #pragma unroll
        for (int n = 0; n < 4; ++n) {
            const int col = colbase + n*16;
            #pragma unroll
            for (int r = 0; r < 4; ++r) {
                const int row = rowbase + m*16 + r;
                float v = acc[m][n][r] + bias_n[n];
                if (EPI == 0) {
                    outb[(size_t)row * ldo + col] = f2bf(v);
                } else if (EPI == 1) {
                    float g = 0.5f * v * (1.0f + erff(v * 0.70710678118654752f));
                    outb[(size_t)row * ldo + col] = f2bf(g);
                } else {
                    if (row < Mvalid) {
                        size_t off = (size_t)row * ldo + col;
                        resid[off] += v;
                    }
                }
            }
        }
    }
}

// ---------------- fused attention: per (q-tile, head, batch) ----------------
__global__ __launch_bounds__(256)
void attn_kernel(u16* __restrict__ Qb, const u16* __restrict__ Kb, const u16* __restrict__ Vb)
{
    const int qt = blockIdx.x, h = blockIdx.y, b = blockIdx.z;
    const int tid = threadIdx.x, wave = tid >> 6, lane = tid & 63;
    const int lr = lane & 15, lk = (lane >> 4) * 8;

    __shared__ __align__(16) u16 VT[64][72];      // V^T, padded rows
    __shared__ __align__(16) u16 P[4][16][72];    // per-wave P tiles

    // stage V transposed: VT[d][k] = V[k][d]
    {
        const int k  = tid >> 2;
        const int d0 = (tid & 3) * 16;
        const u16* vrow = Vb + ((size_t)(b*64 + k)) * 768 + h*64 + d0;
        #pragma unroll
        for (int j = 0; j < 16; ++j) VT[d0 + j][k] = vrow[j];
    }

    const int srow  = qt*64 + wave*16 + lr;
    const int srowc = srow < LQn ? srow : (LQn - 1);
    const u16* qptr = Qb + ((size_t)b*LQn + srowc) * 768 + h*64;
    bf16x8 aq0 = *(const bf16x8*)(qptr + lk);
    bf16x8 aq1 = *(const bf16x8*)(qptr + 32 + lk);

    bf16x8 kf[4][2];
    #pragma unroll
    for (int n = 0; n < 4; ++n) {
        const u16* kptr = Kb + ((size_t)(b*64 + n*16 + lr)) * 768 + h*64;
        kf[n][0] = *(const bf16x8*)(kptr + lk);
        kf[n][1] = *(const bf16x8*)(kptr + 32 + lk);
    }

    f32x4 s[4] = {};
    #pragma unroll
    for (int n = 0; n < 4; ++n) {
        s[n] = __builtin_amdgcn_mfma_f32_16x16x32_bf16(aq0, kf[n][0], s[n], 0, 0, 0);
        s[n] = __builtin_amdgcn_mfma_f32_16x16x32_bf16(aq1, kf[n][1], s[n], 0, 0, 0);
    }

    float p[4][4];
    #pragma unroll
    for (int r = 0; r < 4; ++r) {
        float x0 = s[0][r]*0.125f, x1 = s[1][r]*0.125f;
        float x2 = s[2][r]*0.125f, x3 = s[3][r]*0.125f;
        float mx = fmaxf(fmaxf(x0, x1), fmaxf(x2, x3));
        #pragma unroll
        for (int msk = 1; msk < 16; msk <<= 1) mx = fmaxf(mx, __shfl_xor(mx, msk));
        float e0 = __expf(x0 - mx), e1 = __expf(x1 - mx);
        float e2 = __expf(x2 - mx), e3 = __expf(x3 - mx);
        float sm = e0 + e1 + e2 + e3;
        #pragma unroll
        for (int msk = 1; msk < 16; msk <<= 1) sm += __shfl_xor(sm, msk);
        float inv = 1.0f / sm;
        p[0][r] = e0*inv; p[1][r] = e1*inv; p[2][r] = e2*inv; p[3][r] = e3*inv;
    }

    #pragma unroll
    for (int n = 0; n < 4; ++n)
        #pragma unroll
        for (int r = 0; r < 4; ++r)
            P[wave][(lane >> 4)*4 + r][n*16 + lr] = f2bf(p[n][r]);

    __syncthreads();  // covers VT staging + P writes + all Q/K reads

    f32x4 o[4] = {};
    #pragma unroll
    for (int kk = 0; kk < 2; ++kk) {
        bf16x8 ap = *(const bf16x8*)(&P[wave][lr][kk*32 + lk]);
        #pragma unroll
        for (int n = 0; n < 4; ++n) {
            bf16x8 bv = *(const bf16x8*)(&VT[n*16 + lr][kk*32 + lk]);
            o[n] = __builtin_amdgcn_mfma_f32_16x16x32_bf16(ap, bv, o[n], 0, 0, 0);
        }
    }

    #pragma unroll
    for (int n = 0; n < 4; ++n) {
        const int d = n*16 + lr;
        #pragma unroll
        for (int r = 0; r < 4; ++r) {
            const int so = qt*64 + wave*16 + (lane >> 4)*4 + r;
            if (so < LQn)
                Qb[((size_t)b*LQn + so) * 768 + h*64 + d] = f2bf(o[n][r]);
        }
    }
}

// ---------------- LayerNorm f32 -> bf16, 1 wave per row ----------------
__global__ __launch_bounds__(256)
void ln_kernel(const float* __restrict__ X, const float* __restrict__ g,
               const float* __restrict__ bta, u16* __restrict__ Y, int rows_valid)
{
    const int wave = threadIdx.x >> 6, lane = threadIdx.x & 63;
    const int row = blockIdx.x * 4 + wave;
    u16* yr = Y + (size_t)row * DD;
    if (row >= rows_valid) {   // pad rows: write zeros
        #pragma unroll
        for (int i = 0; i < 3; ++i)
            *(ushort4*)(yr + i*256 + lane*4) = make_ushort4(0, 0, 0, 0);
        return;
    }
    const float* xr = X + (size_t)row * DD;
    float4 v[3];
    float s = 0.f, s2 = 0.f;
    #pragma unroll
    for (int i = 0; i < 3; ++i) {
        v[i] = *(const float4*)(xr + i*256 + lane*4);
        s  += v[i].x + v[i].y + v[i].z + v[i].w;
        s2 += v[i].x*v[i].x + v[i].y*v[i].y + v[i].z*v[i].z + v[i].w*v[i].w;
    }
    #pragma unroll
    for (int m = 1; m < 64; m <<= 1) { s += __shfl_xor(s, m); s2 += __shfl_xor(s2, m); }
    const float mean = s * (1.f/768.f);
    const float var  = s2 * (1.f/768.f) - mean*mean;
    const float rstd = rsqrtf(var + 1e-5f);
    #pragma unroll
    for (int i = 0; i < 3; ++i) {
        float4 gg = *(const float4*)(g   + i*256 + lane*4);
        float4 bb = *(const float4*)(bta + i*256 + lane*4);
        ushort4 ov;
        ov.x = f2bf((v[i].x - mean)*rstd*gg.x + bb.x);
        ov.y = f2bf((v[i].y - mean)*rstd*gg.y + bb.y);
        ov.z = f2bf((v[i].z - mean)*rstd*gg.z + bb.z);
        ov.w = f2bf((v[i].w - mean)*rstd*gg.w + bb.w);
        *(ushort4*)(yr + i*256 + lane*4) = ov;
    }
}

// ---------------- helpers ----------------
__global__ __launch_bounds__(256)
void cvt_kernel(const float* __restrict__ in, u16* __restrict__ out, long long n)
{
    long long i = ((long long)blockIdx.x * blockDim.x + threadIdx.x) * 4;
    const long long stride = (long long)gridDim.x * blockDim.x * 4;
    for (; i < n; i += stride) {
        float4 v = *(const float4*)(in + i);
        ushort4 o;
        o.x = f2bf(v.x); o.y = f2bf(v.y); o.z = f2bf(v.z); o.w = f2bf(v.w);
        *(ushort4*)(out + i) = o;
    }
}

__global__ __launch_bounds__(256)
void copy_kernel(const float* __restrict__ in, float* __restrict__ out, long long n)
{
    long long i = ((long long)blockIdx.x * blockDim.x + threadIdx.x) * 4;
    const long long stride = (long long)gridDim.x * blockDim.x * 4;
    for (; i < n; i += stride)
        *(float4*)(out + i) = *(const float4*)(in + i);
}

extern "C" void kernel_launch(void* const* d_in, const int* in_sizes, int n_in,
                              void* d_out, int out_size, void* d_ws, size_t ws_size,
                              hipStream_t stream)
{
    (void)in_sizes; (void)n_in; (void)out_size; (void)ws_size;

    const float* query     = (const float*)d_in[0];
    const float* key_value = (const float*)d_in[1];
    const float* ln1q_g = (const float*)d_in[2];
    const float* ln1q_b = (const float*)d_in[3];
    const float* ln1kv_g = (const float*)d_in[4];
    const float* ln1kv_b = (const float*)d_in[5];
    const float* wq = (const float*)d_in[6];
    const float* bq = (const float*)d_in[7];
    const float* wk = (const float*)d_in[8];
    const float* bk = (const float*)d_in[9];
    const float* wv = (const float*)d_in[10];
    const float* bv = (const float*)d_in[11];
    const float* wo = (const float*)d_in[12];
    const float* bo = (const float*)d_in[13];
    const float* ln2_g = (const float*)d_in[14];
    const float* ln2_b = (const float*)d_in[15];
    const float* w1 = (const float*)d_in[16];
    const float* b1 = (const float*)d_in[17];
    const float* w2 = (const float*)d_in[18];
    const float* b2 = (const float*)d_in[19];
    float* resid = (float*)d_out;

    // ---- workspace carve: ~140 MB total ----
    char* p = (char*)d_ws;
    auto carve = [&](size_t elems) {
        u16* r = (u16*)p;
        p += ((elems * 2 + 255) & ~(size_t)255);
        return r;
    };
    u16* wl_q = carve((size_t)DD*DD);      // per-layer bf16 weights (reused)
    u16* wl_k = carve((size_t)DD*DD);
    u16* wl_v = carve((size_t)DD*DD);
    u16* wl_o = carve((size_t)DD*DD);
    u16* wl_1 = carve((size_t)FFN*DD);
    u16* wl_2 = carve((size_t)DD*FFN);
    u16* Xbf  = carve((size_t)MQP*DD);
    u16* Qbuf = carve((size_t)MQP*DD);     // also aliased as H1 chunk during FFN
    u16* KVn  = carve((size_t)MKV*DD);
    u16* Kbuf = carve((size_t)MKV*DD);
    u16* Vbuf = carve((size_t)MKV*DD);
    u16* H1c  = Qbuf;                      // CHROWS*FFN = 25.2M elems <= MQP*DD = 28.4M

    copy_kernel<<<2048, 256, 0, stream>>>(query, resid, (long long)MQ*DD);

    for (int l = 0; l < DEPTH; ++l) {
        // per-layer weight bf16 conversion
        cvt_kernel<<<576, 256, 0, stream>>>(wq + (size_t)l*DD*DD, wl_q, (long long)DD*DD);
        cvt_kernel<<<576, 256, 0, stream>>>(wk + (size_t)l*DD*DD, wl_k, (long long)DD*DD);
        cvt_kernel<<<576, 256, 0, stream>>>(wv + (size_t)l*DD*DD, wl_v, (long long)DD*DD);
        cvt_kernel<<<576, 256, 0, stream>>>(wo + (size_t)l*DD*DD, wl_o, (long long)DD*DD);
        cvt_kernel<<<2304, 256, 0, stream>>>(w1 + (size_t)l*FFN*DD, wl_1, (long long)FFN*DD);
        cvt_kernel<<<2304, 256, 0, stream>>>(w2 + (size_t)l*DD*FFN, wl_2, (long long)DD*FFN);

        ln_kernel<<<MQP/4, 256, 0, stream>>>(resid, ln1q_g + l*DD, ln1q_b + l*DD, Xbf, MQ);
        ln_kernel<<<MKV/4, 256, 0, stream>>>(key_value, ln1kv_g + l*DD, ln1kv_b + l*DD, KVn, MKV);

        gemm_bt<0><<<dim3(MQP/128, DD/128), 256, 0, stream>>>(
            Xbf, DD, wl_q, DD, bq + l*DD, Qbuf, nullptr, DD, MQP, DD);
        gemm_bt<0><<<dim3(MKV/128, DD/128), 256, 0, stream>>>(
            KVn, DD, wl_k, DD, bk + l*DD, Kbuf, nullptr, DD, MKV, DD);
        gemm_bt<0><<<dim3(MKV/128, DD/128), 256, 0, stream>>>(
            KVn, DD, wl_v, DD, bv + l*DD, Vbuf, nullptr, DD, MKV, DD);

        attn_kernel<<<dim3(10, HH, BB), 256, 0, stream>>>(Qbuf, Kbuf, Vbuf);

        gemm_bt<2><<<dim3(MQP/128, DD/128), 256, 0, stream>>>(
            Qbuf, DD, wl_o, DD, bo + l*DD, nullptr, resid, DD, MQ, DD);

        ln_kernel<<<MQP/4, 256, 0, stream>>>(resid, ln2_g + l*DD, ln2_b + l*DD, Xbf, MQ);

        // FFN in M-chunks (H1c aliases Qbuf, which is dead here)
        for (int ch0 = 0; ch0 < MQP; ch0 += CHROWS) {
            const int nb = ((MQP - ch0) < CHROWS ? (MQP - ch0) : CHROWS) / 128;
            gemm_bt<1><<<dim3(nb, FFN/128), 256, 0, stream>>>(
                Xbf + (size_t)ch0 * DD, DD, wl_1, DD, b1 + l*FFN, H1c, nullptr, FFN, nb*128, DD);
            gemm_bt<2><<<dim3(nb, DD/128), 256, 0, stream>>>(
                H1c, FFN, wl_2, FFN, b2 + l*DD, nullptr, resid + (size_t)ch0 * DD, DD,
                MQ - ch0, FFN);
        }
    }
}